// Round 1
// baseline (241.833 us; speedup 1.0000x reference)
//
#include <hip/hip_runtime.h>
#include <math.h>

#define N_ 16
#define C_ 256
#define H_ 128
#define W_ 128
#define TC_ 8
#define S_ 257   // H + W + 1
#define EPS_ 1e-5f

// ws layout (floats):
//   xcat: [N*C][S][2]  = 4096*257*2 = 2105344
//   a_h : [N*C][H]     = 524288
//   a_w : [N*C][W]     = 524288
//   a_c : [N*C]        = 4096
#define XCAT_OFF 0
#define AH_OFF   2105344
#define AW_OFF   (AH_OFF + 524288)
#define AC_OFF   (AW_OFF + 524288)

__global__ __launch_bounds__(256) void k1_stats(const float* __restrict__ x,
                                                float* __restrict__ xcat) {
    const int bc = blockIdx.x;                // n*C + c
    const int tid = threadIdx.x;
    const float4* xt = reinterpret_cast<const float4*>(x) + (size_t)bc * 4096;
    float2* xcat2 = reinterpret_cast<float2*>(xcat) + (size_t)bc * S_;

    __shared__ float4 scr_s[4][32];
    __shared__ float4 scr_m[4][32];

    float4 cs = make_float4(0.f, 0.f, 0.f, 0.f);
    float4 cm = make_float4(-INFINITY, -INFINITY, -INFINITY, -INFINITY);

    // Each thread's float4 lands on fixed columns 4*(tid&31)+{0..3},
    // rows h = k*8 + (tid>>5), k = 0..15.
    #pragma unroll
    for (int k = 0; k < 16; ++k) {
        const int i4 = k * 256 + tid;
        const float4 v = xt[i4];
        cs.x += v.x; cs.y += v.y; cs.z += v.z; cs.w += v.w;
        cm.x = fmaxf(cm.x, v.x); cm.y = fmaxf(cm.y, v.y);
        cm.z = fmaxf(cm.z, v.z); cm.w = fmaxf(cm.w, v.w);

        // row partial: 32 lanes (contiguous tids) share one row
        float rs = (v.x + v.y) + (v.z + v.w);
        float rm = fmaxf(fmaxf(v.x, v.y), fmaxf(v.z, v.w));
        #pragma unroll
        for (int m = 16; m >= 1; m >>= 1) {
            rs += __shfl_xor(rs, m);
            rm = fmaxf(rm, __shfl_xor(rm, m));
        }
        if ((tid & 31) == 0) {
            const int h = k * 8 + (tid >> 5);
            xcat2[h] = make_float2(rs * (1.f / 128.f), rm);
        }
    }

    // combine column partials: pair groups within wave (xor 32)
    cs.x += __shfl_xor(cs.x, 32); cs.y += __shfl_xor(cs.y, 32);
    cs.z += __shfl_xor(cs.z, 32); cs.w += __shfl_xor(cs.w, 32);
    cm.x = fmaxf(cm.x, __shfl_xor(cm.x, 32));
    cm.y = fmaxf(cm.y, __shfl_xor(cm.y, 32));
    cm.z = fmaxf(cm.z, __shfl_xor(cm.z, 32));
    cm.w = fmaxf(cm.w, __shfl_xor(cm.w, 32));

    const int wv = tid >> 6, ln = tid & 63;
    if (ln < 32) { scr_s[wv][ln] = cs; scr_m[wv][ln] = cm; }
    __syncthreads();

    if (tid < 32) {
        const float4 s0 = scr_s[0][tid], s1 = scr_s[1][tid],
                     s2 = scr_s[2][tid], s3 = scr_s[3][tid];
        const float4 m0 = scr_m[0][tid], m1 = scr_m[1][tid],
                     m2 = scr_m[2][tid], m3 = scr_m[3][tid];
        float4 S, M;
        S.x = (s0.x + s1.x) + (s2.x + s3.x);
        S.y = (s0.y + s1.y) + (s2.y + s3.y);
        S.z = (s0.z + s1.z) + (s2.z + s3.z);
        S.w = (s0.w + s1.w) + (s2.w + s3.w);
        M.x = fmaxf(fmaxf(m0.x, m1.x), fmaxf(m2.x, m3.x));
        M.y = fmaxf(fmaxf(m0.y, m1.y), fmaxf(m2.y, m3.y));
        M.z = fmaxf(fmaxf(m0.z, m1.z), fmaxf(m2.z, m3.z));
        M.w = fmaxf(fmaxf(m0.w, m1.w), fmaxf(m2.w, m3.w));

        // column stats (s index 128 + w)
        const int w0 = 4 * tid;
        xcat2[128 + w0 + 0] = make_float2(S.x * (1.f / 128.f), M.x);
        xcat2[128 + w0 + 1] = make_float2(S.y * (1.f / 128.f), M.y);
        xcat2[128 + w0 + 2] = make_float2(S.z * (1.f / 128.f), M.z);
        xcat2[128 + w0 + 3] = make_float2(S.w * (1.f / 128.f), M.w);

        // global stats
        float gs = (S.x + S.y) + (S.z + S.w);
        float gm = fmaxf(fmaxf(M.x, M.y), fmaxf(M.z, M.w));
        #pragma unroll
        for (int m = 16; m >= 1; m >>= 1) {
            gs += __shfl_xor(gs, m);
            gm = fmaxf(gm, __shfl_xor(gm, m));
        }
        if (tid == 0) xcat2[256] = make_float2(gs * (1.f / 16384.f), gm);
    }
}

__global__ __launch_bounds__(256) void k2_attn(
    const float* __restrict__ xcat,
    const float* __restrict__ w1, const float* __restrict__ b1,
    const float* __restrict__ gam, const float* __restrict__ bet,
    const float* __restrict__ mu, const float* __restrict__ var,
    const float* __restrict__ w2, const float* __restrict__ b2,
    const float* __restrict__ w3, const float* __restrict__ b3,
    const float* __restrict__ w4, const float* __restrict__ b4,
    float* __restrict__ a_h, float* __restrict__ a_w, float* __restrict__ a_c) {
    const int n = blockIdx.x;
    const int tid = threadIdx.x;

    __shared__ float w1s[TC_ * C_];       // 2048
    __shared__ float w2s[C_ * TC_ * 2];   // 4096
    __shared__ float w3s[C_ * TC_ * 2];   // 4096
    __shared__ float ys[TC_ * S_ * 2];    // 4112

    for (int i = tid; i < TC_ * C_; i += 256) w1s[i] = w1[i];
    for (int i = tid; i < C_ * TC_ * 2; i += 256) { w2s[i] = w2[i]; w3s[i] = w3[i]; }
    __syncthreads();

    // phase 1: y[t,s,k] = BN(hsw?) -> actually BN then hswish
    const float2* xc = reinterpret_cast<const float2*>(xcat) + (size_t)n * C_ * S_;
    for (int s = tid; s < S_; s += 256) {
        float acc0[TC_], acc1[TC_];
        #pragma unroll
        for (int t = 0; t < TC_; ++t) { acc0[t] = 0.f; acc1[t] = 0.f; }
        for (int c = 0; c < C_; ++c) {
            const float2 v = xc[c * S_ + s];
            #pragma unroll
            for (int t = 0; t < TC_; ++t) {
                const float wv = w1s[t * C_ + c];
                acc0[t] += v.x * wv;
                acc1[t] += v.y * wv;
            }
        }
        #pragma unroll
        for (int t = 0; t < TC_; ++t) {
            const float inv = gam[t] / sqrtf(var[t] + EPS_);
            const float base = b1[t] - mu[t];
            float y0 = (acc0[t] + base) * inv + bet[t];
            float y1 = (acc1[t] + base) * inv + bet[t];
            y0 = y0 * fminf(fmaxf(y0 + 3.f, 0.f), 6.f) * (1.f / 6.f);
            y1 = y1 * fminf(fmaxf(y1 + 3.f, 0.f), 6.f) * (1.f / 6.f);
            ys[(t * S_ + s) * 2 + 0] = y0;
            ys[(t * S_ + s) * 2 + 1] = y1;
        }
    }
    __syncthreads();

    // phase 2
    const int hw = tid & 127, half = tid >> 7;
    {
        float yh[16];
        #pragma unroll
        for (int t = 0; t < TC_; ++t) {
            yh[t * 2 + 0] = ys[(t * S_ + hw) * 2 + 0];
            yh[t * 2 + 1] = ys[(t * S_ + hw) * 2 + 1];
        }
        for (int oo = 0; oo < 128; ++oo) {
            const int o = half * 128 + oo;
            float z = b2[o];
            #pragma unroll
            for (int j = 0; j < 16; ++j) z += yh[j] * w2s[o * 16 + j];
            a_h[((size_t)n * C_ + o) * H_ + hw] = 1.f / (1.f + expf(-z));
        }
    }
    {
        float yw[16];
        #pragma unroll
        for (int t = 0; t < TC_; ++t) {
            yw[t * 2 + 0] = ys[(t * S_ + 128 + hw) * 2 + 0];
            yw[t * 2 + 1] = ys[(t * S_ + 128 + hw) * 2 + 1];
        }
        for (int oo = 0; oo < 128; ++oo) {
            const int o = half * 128 + oo;
            float z = b3[o];
            #pragma unroll
            for (int j = 0; j < 16; ++j) z += yw[j] * w3s[o * 16 + j];
            a_w[((size_t)n * C_ + o) * W_ + hw] = 1.f / (1.f + expf(-z));
        }
    }
    {
        float yc[16];
        #pragma unroll
        for (int t = 0; t < TC_; ++t) {
            yc[t * 2 + 0] = ys[(t * S_ + 256) * 2 + 0];
            yc[t * 2 + 1] = ys[(t * S_ + 256) * 2 + 1];
        }
        const int o = tid;
        float z = b4[o];
        const float4* w4v = reinterpret_cast<const float4*>(w4);
        #pragma unroll
        for (int j4 = 0; j4 < 4; ++j4) {
            const float4 ww = w4v[o * 4 + j4];
            z += yc[j4 * 4 + 0] * ww.x + yc[j4 * 4 + 1] * ww.y +
                 yc[j4 * 4 + 2] * ww.z + yc[j4 * 4 + 3] * ww.w;
        }
        a_c[n * C_ + o] = 1.f / (1.f + expf(-z));
    }
}

__global__ __launch_bounds__(256) void k3_apply(
    const float* __restrict__ x, const float* __restrict__ a_h,
    const float* __restrict__ a_w, const float* __restrict__ a_c,
    float* __restrict__ out) {
    const int bc = blockIdx.x;
    const int tid = threadIdx.x;
    const float4* x4 = reinterpret_cast<const float4*>(x) + (size_t)bc * 4096;
    float4* o4 = reinterpret_cast<float4*>(out) + (size_t)bc * 4096;
    const float ac = a_c[bc];
    const float* ah = a_h + (size_t)bc * H_;
    const float4* aw4 = reinterpret_cast<const float4*>(a_w) + (size_t)bc * 32;

    #pragma unroll
    for (int k = 0; k < 16; ++k) {
        const int i4 = k * 256 + tid;
        float4 v = x4[i4];
        const float s = ah[i4 >> 5] * ac;
        const float4 a = aw4[i4 & 31];
        v.x *= s * a.x; v.y *= s * a.y; v.z *= s * a.z; v.w *= s * a.w;
        o4[i4] = v;
    }
}

extern "C" void kernel_launch(void* const* d_in, const int* in_sizes, int n_in,
                              void* d_out, int out_size, void* d_ws, size_t ws_size,
                              hipStream_t stream) {
    const float* x   = (const float*)d_in[0];
    const float* w1  = (const float*)d_in[1];
    const float* b1  = (const float*)d_in[2];
    const float* gam = (const float*)d_in[3];
    const float* bet = (const float*)d_in[4];
    const float* mu  = (const float*)d_in[5];
    const float* var = (const float*)d_in[6];
    const float* w2  = (const float*)d_in[7];
    const float* b2  = (const float*)d_in[8];
    const float* w3  = (const float*)d_in[9];
    const float* b3  = (const float*)d_in[10];
    const float* w4  = (const float*)d_in[11];
    const float* b4  = (const float*)d_in[12];

    float* ws   = (float*)d_ws;
    float* xcat = ws + XCAT_OFF;
    float* a_h  = ws + AH_OFF;
    float* a_w  = ws + AW_OFF;
    float* a_c  = ws + AC_OFF;
    float* out  = (float*)d_out;

    k1_stats<<<N_ * C_, 256, 0, stream>>>(x, xcat);
    k2_attn<<<N_, 256, 0, stream>>>(xcat, w1, b1, gam, bet, mu, var,
                                    w2, b2, w3, b3, w4, b4, a_h, a_w, a_c);
    k3_apply<<<N_ * C_, 256, 0, stream>>>(x, a_h, a_w, a_c, out);
}

// Round 2
// 236.092 us; speedup vs baseline: 1.0243x; 1.0243x over previous
//
#include <hip/hip_runtime.h>
#include <math.h>

#define N_ 16
#define C_ 256
#define H_ 128
#define W_ 128
#define TC_ 8
#define S_ 257   // H + W + 1
#define EPS_ 1e-5f

// ws layout (floats):
//   xcat: [N*C][S][2]          = 2105344
//   y   : [N][S][16]  (t*2+k)  = 65792
//   a_h : [N*C][H]  (includes a_c factor) = 524288
//   a_w : [N*C][W]             = 524288
#define XCAT_OFF 0
#define Y_OFF    2105344
#define AH_OFF   (Y_OFF + 65792)
#define AW_OFF   (AH_OFF + 524288)

__global__ __launch_bounds__(256) void k1_stats(const float* __restrict__ x,
                                                float* __restrict__ xcat) {
    const int bc = blockIdx.x;                // n*C + c
    const int tid = threadIdx.x;
    const float4* xt = reinterpret_cast<const float4*>(x) + (size_t)bc * 4096;
    float2* xcat2 = reinterpret_cast<float2*>(xcat) + (size_t)bc * S_;

    __shared__ float2 rowp[128][33];          // padded: conflict-free
    __shared__ float4 scr_s[4][32];
    __shared__ float4 scr_m[4][32];

    float4 cs = make_float4(0.f, 0.f, 0.f, 0.f);
    float4 cm = make_float4(-INFINITY, -INFINITY, -INFINITY, -INFINITY);

    const int rg = tid >> 5, l = tid & 31;

    // Each thread's float4 covers columns 4*l+{0..3}, row h = k*8 + rg.
    #pragma unroll
    for (int k = 0; k < 16; ++k) {
        const float4 v = xt[k * 256 + tid];
        cs.x += v.x; cs.y += v.y; cs.z += v.z; cs.w += v.w;
        cm.x = fmaxf(cm.x, v.x); cm.y = fmaxf(cm.y, v.y);
        cm.z = fmaxf(cm.z, v.z); cm.w = fmaxf(cm.w, v.w);
        const float rs = (v.x + v.y) + (v.z + v.w);
        const float rm = fmaxf(fmaxf(v.x, v.y), fmaxf(v.z, v.w));
        rowp[k * 8 + rg][l] = make_float2(rs, rm);
    }

    // column partials: pair groups within wave (xor 32)
    cs.x += __shfl_xor(cs.x, 32); cs.y += __shfl_xor(cs.y, 32);
    cs.z += __shfl_xor(cs.z, 32); cs.w += __shfl_xor(cs.w, 32);
    cm.x = fmaxf(cm.x, __shfl_xor(cm.x, 32));
    cm.y = fmaxf(cm.y, __shfl_xor(cm.y, 32));
    cm.z = fmaxf(cm.z, __shfl_xor(cm.z, 32));
    cm.w = fmaxf(cm.w, __shfl_xor(cm.w, 32));

    const int wv = tid >> 6, ln = tid & 63;
    if (ln < 32) { scr_s[wv][ln] = cs; scr_m[wv][ln] = cm; }
    __syncthreads();

    // waves 2-3: row stats (h = tid-128)
    if (tid >= 128) {
        const int h = tid - 128;
        float2 p = rowp[h][0];
        float s = p.x, m = p.y;
        #pragma unroll
        for (int j = 1; j < 32; ++j) {
            const float2 q = rowp[h][j];
            s += q.x; m = fmaxf(m, q.y);
        }
        xcat2[h] = make_float2(s * (1.f / 128.f), m);
    }

    // wave 0 (lanes<32): columns + global
    if (tid < 32) {
        const float4 s0 = scr_s[0][tid], s1 = scr_s[1][tid],
                     s2 = scr_s[2][tid], s3 = scr_s[3][tid];
        const float4 m0 = scr_m[0][tid], m1 = scr_m[1][tid],
                     m2 = scr_m[2][tid], m3 = scr_m[3][tid];
        float4 S, M;
        S.x = (s0.x + s1.x) + (s2.x + s3.x);
        S.y = (s0.y + s1.y) + (s2.y + s3.y);
        S.z = (s0.z + s1.z) + (s2.z + s3.z);
        S.w = (s0.w + s1.w) + (s2.w + s3.w);
        M.x = fmaxf(fmaxf(m0.x, m1.x), fmaxf(m2.x, m3.x));
        M.y = fmaxf(fmaxf(m0.y, m1.y), fmaxf(m2.y, m3.y));
        M.z = fmaxf(fmaxf(m0.z, m1.z), fmaxf(m2.z, m3.z));
        M.w = fmaxf(fmaxf(m0.w, m1.w), fmaxf(m2.w, m3.w));

        const int w0 = 4 * tid;
        xcat2[128 + w0 + 0] = make_float2(S.x * (1.f / 128.f), M.x);
        xcat2[128 + w0 + 1] = make_float2(S.y * (1.f / 128.f), M.y);
        xcat2[128 + w0 + 2] = make_float2(S.z * (1.f / 128.f), M.z);
        xcat2[128 + w0 + 3] = make_float2(S.w * (1.f / 128.f), M.w);

        float gs = (S.x + S.y) + (S.z + S.w);
        float gm = fmaxf(fmaxf(M.x, M.y), fmaxf(M.z, M.w));
        #pragma unroll
        for (int m = 16; m >= 1; m >>= 1) {
            gs += __shfl_xor(gs, m);
            gm = fmaxf(gm, __shfl_xor(gm, m));
        }
        if (tid == 0) xcat2[256] = make_float2(gs * (1.f / 16384.f), gm);
    }
}

// y[n][s][t*2+k] = hswish(BN(einsum)) — grid N*9, 8-way c-split per s-chunk of 32
__global__ __launch_bounds__(256) void k2a_y(
    const float* __restrict__ xcat,
    const float* __restrict__ w1, const float* __restrict__ b1,
    const float* __restrict__ gam, const float* __restrict__ bet,
    const float* __restrict__ mu, const float* __restrict__ var,
    float* __restrict__ yg) {
    const int n = blockIdx.x / 9, sc = blockIdx.x % 9;
    const int tid = threadIdx.x;
    const int sl = tid & 31, cg = tid >> 5;

    __shared__ float w1s[TC_ * C_];           // 8 KB
    __shared__ float red[8][32 * 17];         // padded

    for (int i = tid; i < TC_ * C_; i += 256) w1s[i] = w1[i];
    __syncthreads();

    const int s = sc * 32 + sl;
    float acc[16];
    #pragma unroll
    for (int j = 0; j < 16; ++j) acc[j] = 0.f;

    if (s < S_) {
        const float2* xc = reinterpret_cast<const float2*>(xcat) + (size_t)n * C_ * S_;
        for (int ci = 0; ci < 32; ++ci) {
            const int c = cg * 32 + ci;
            const float2 v = xc[c * S_ + s];
            #pragma unroll
            for (int t = 0; t < TC_; ++t) {
                const float wv = w1s[t * C_ + c];
                acc[t * 2 + 0] += v.x * wv;
                acc[t * 2 + 1] += v.y * wv;
            }
        }
    }
    #pragma unroll
    for (int j = 0; j < 16; ++j) red[cg][sl * 17 + j] = acc[j];
    __syncthreads();

    // reduce 8 c-groups; thread (jj, sl2) handles j = 2*jj, 2*jj+1
    const int jj = tid >> 5, sl2 = tid & 31;
    const int s2 = sc * 32 + sl2;
    if (s2 < S_) {
        #pragma unroll
        for (int d = 0; d < 2; ++d) {
            const int j = jj * 2 + d;
            float v = 0.f;
            #pragma unroll
            for (int g = 0; g < 8; ++g) v += red[g][sl2 * 17 + j];
            const int t = j >> 1;
            const float inv = gam[t] * rsqrtf(var[t] + EPS_);
            float y = (v + b1[t] - mu[t]) * inv + bet[t];
            y = y * fminf(fmaxf(y + 3.f, 0.f), 6.f) * (1.f / 6.f);
            yg[((size_t)n * S_ + s2) * 16 + j] = y;
        }
    }
}

__global__ __launch_bounds__(256) void k2b_attn(
    const float* __restrict__ yg,
    const float* __restrict__ w2, const float* __restrict__ b2,
    const float* __restrict__ w3, const float* __restrict__ b3,
    const float* __restrict__ w4, const float* __restrict__ b4,
    float* __restrict__ a_h, float* __restrict__ a_w) {
    const int n = blockIdx.x;
    const int tid = threadIdx.x;

    __shared__ float w2s[C_ * 16];    // 16 KB
    __shared__ float w3s[C_ * 16];    // 16 KB
    __shared__ float ys[S_ * 17];     // padded, 17.5 KB
    __shared__ float acs[C_];

    for (int i = tid; i < C_ * 16; i += 256) { w2s[i] = w2[i]; w3s[i] = w3[i]; }
    for (int i = tid; i < S_ * 16; i += 256) {
        ys[(i >> 4) * 17 + (i & 15)] = yg[(size_t)n * S_ * 16 + i];
    }
    __syncthreads();

    // a_c per output channel o = tid
    {
        float z = b4[tid];
        const float4* w4v = reinterpret_cast<const float4*>(w4) + tid * 4;
        #pragma unroll
        for (int q = 0; q < 4; ++q) {
            const float4 ww = w4v[q];
            z += ys[256 * 17 + q * 4 + 0] * ww.x + ys[256 * 17 + q * 4 + 1] * ww.y +
                 ys[256 * 17 + q * 4 + 2] * ww.z + ys[256 * 17 + q * 4 + 3] * ww.w;
        }
        acs[tid] = 1.f / (1.f + expf(-z));
    }
    __syncthreads();

    const int hw = tid & 127, half = tid >> 7;
    float yh[16], yw[16];
    #pragma unroll
    for (int j = 0; j < 16; ++j) {
        yh[j] = ys[hw * 17 + j];
        yw[j] = ys[(128 + hw) * 17 + j];
    }
    for (int oo = 0; oo < 128; ++oo) {
        const int o = half * 128 + oo;
        float zh = b2[o], zw = b3[o];
        #pragma unroll
        for (int j = 0; j < 16; ++j) {
            zh += yh[j] * w2s[o * 16 + j];
            zw += yw[j] * w3s[o * 16 + j];
        }
        // fold a_c into a_h
        a_h[((size_t)n * C_ + o) * H_ + hw] = acs[o] / (1.f + expf(-zh));
        a_w[((size_t)n * C_ + o) * W_ + hw] = 1.f / (1.f + expf(-zw));
    }
}

__global__ __launch_bounds__(256) void k3_apply(
    const float* __restrict__ x, const float* __restrict__ a_h,
    const float* __restrict__ a_w, float* __restrict__ out) {
    // reverse block order: tail of x is hot in LLC after k1's forward stream
    const int bc = (N_ * C_ - 1) - blockIdx.x;
    const int tid = threadIdx.x;
    const float4* x4 = reinterpret_cast<const float4*>(x) + (size_t)bc * 4096;
    float4* o4 = reinterpret_cast<float4*>(out) + (size_t)bc * 4096;
    const float* ah = a_h + (size_t)bc * H_;   // includes a_c
    const float4* aw4 = reinterpret_cast<const float4*>(a_w) + (size_t)bc * 32;

    #pragma unroll
    for (int k = 0; k < 16; ++k) {
        const int i4 = k * 256 + tid;
        float4 v = x4[i4];
        const float s = ah[i4 >> 5];
        const float4 a = aw4[i4 & 31];
        v.x *= s * a.x; v.y *= s * a.y; v.z *= s * a.z; v.w *= s * a.w;
        o4[i4] = v;
    }
}

extern "C" void kernel_launch(void* const* d_in, const int* in_sizes, int n_in,
                              void* d_out, int out_size, void* d_ws, size_t ws_size,
                              hipStream_t stream) {
    const float* x   = (const float*)d_in[0];
    const float* w1  = (const float*)d_in[1];
    const float* b1  = (const float*)d_in[2];
    const float* gam = (const float*)d_in[3];
    const float* bet = (const float*)d_in[4];
    const float* mu  = (const float*)d_in[5];
    const float* var = (const float*)d_in[6];
    const float* w2  = (const float*)d_in[7];
    const float* b2  = (const float*)d_in[8];
    const float* w3  = (const float*)d_in[9];
    const float* b3  = (const float*)d_in[10];
    const float* w4  = (const float*)d_in[11];
    const float* b4  = (const float*)d_in[12];

    float* ws   = (float*)d_ws;
    float* xcat = ws + XCAT_OFF;
    float* yg   = ws + Y_OFF;
    float* a_h  = ws + AH_OFF;
    float* a_w  = ws + AW_OFF;
    float* out  = (float*)d_out;

    k1_stats<<<N_ * C_, 256, 0, stream>>>(x, xcat);
    k2a_y<<<N_ * 9, 256, 0, stream>>>(xcat, w1, b1, gam, bet, mu, var, yg);
    k2b_attn<<<N_, 256, 0, stream>>>(yg, w2, b2, w3, b3, w4, b4, a_h, a_w);
    k3_apply<<<N_ * C_, 256, 0, stream>>>(x, a_h, a_w, out);
}

// Round 4
// 208.008 us; speedup vs baseline: 1.1626x; 1.1350x over previous
//
#include <hip/hip_runtime.h>
#include <math.h>

#define N_ 16
#define C_ 256
#define H_ 128
#define W_ 128
#define TC_ 8
#define S_ 257   // H + W + 1
#define EPS_ 1e-5f

// ws layout (floats):
//   xcat: [N*C][S][2]          = 2105344
//   y   : [N][S][16]  (t*2+k)  = 65792
//   a_h : [N*C][H]  (includes a_c factor) = 524288
//   a_w : [N*C][W]             = 524288
#define XCAT_OFF 0
#define Y_OFF    2105344
#define AH_OFF   (Y_OFF + 65792)
#define AW_OFF   (AH_OFF + 524288)

typedef float f4n __attribute__((ext_vector_type(4)));

__global__ __launch_bounds__(256) void k1_stats(const float* __restrict__ x,
                                                float* __restrict__ xcat) {
    const int bc = blockIdx.x;                // n*C + c
    const int tid = threadIdx.x;
    const float4* xt = reinterpret_cast<const float4*>(x) + (size_t)bc * 4096;
    float2* xcat2 = reinterpret_cast<float2*>(xcat) + (size_t)bc * S_;

    __shared__ float2 rowp[128][33];          // padded: conflict-free
    __shared__ float4 scr_s[4][32];
    __shared__ float4 scr_m[4][32];

    float4 cs = make_float4(0.f, 0.f, 0.f, 0.f);
    float4 cm = make_float4(-INFINITY, -INFINITY, -INFINITY, -INFINITY);

    const int rg = tid >> 5, l = tid & 31;

    // Each thread's float4 covers columns 4*l+{0..3}, row h = k*8 + rg.
    #pragma unroll
    for (int k = 0; k < 16; ++k) {
        const float4 v = xt[k * 256 + tid];
        cs.x += v.x; cs.y += v.y; cs.z += v.z; cs.w += v.w;
        cm.x = fmaxf(cm.x, v.x); cm.y = fmaxf(cm.y, v.y);
        cm.z = fmaxf(cm.z, v.z); cm.w = fmaxf(cm.w, v.w);
        const float rs = (v.x + v.y) + (v.z + v.w);
        const float rm = fmaxf(fmaxf(v.x, v.y), fmaxf(v.z, v.w));
        rowp[k * 8 + rg][l] = make_float2(rs, rm);
    }

    // column partials: pair groups within wave (xor 32)
    cs.x += __shfl_xor(cs.x, 32); cs.y += __shfl_xor(cs.y, 32);
    cs.z += __shfl_xor(cs.z, 32); cs.w += __shfl_xor(cs.w, 32);
    cm.x = fmaxf(cm.x, __shfl_xor(cm.x, 32));
    cm.y = fmaxf(cm.y, __shfl_xor(cm.y, 32));
    cm.z = fmaxf(cm.z, __shfl_xor(cm.z, 32));
    cm.w = fmaxf(cm.w, __shfl_xor(cm.w, 32));

    const int wv = tid >> 6, ln = tid & 63;
    if (ln < 32) { scr_s[wv][ln] = cs; scr_m[wv][ln] = cm; }
    __syncthreads();

    // waves 2-3: row stats (h = tid-128)
    if (tid >= 128) {
        const int h = tid - 128;
        float2 p = rowp[h][0];
        float s = p.x, m = p.y;
        #pragma unroll
        for (int j = 1; j < 32; ++j) {
            const float2 q = rowp[h][j];
            s += q.x; m = fmaxf(m, q.y);
        }
        xcat2[h] = make_float2(s * (1.f / 128.f), m);
    }

    // wave 0 (lanes<32): columns + global
    if (tid < 32) {
        const float4 s0 = scr_s[0][tid], s1 = scr_s[1][tid],
                     s2 = scr_s[2][tid], s3 = scr_s[3][tid];
        const float4 m0 = scr_m[0][tid], m1 = scr_m[1][tid],
                     m2 = scr_m[2][tid], m3 = scr_m[3][tid];
        float4 S, M;
        S.x = (s0.x + s1.x) + (s2.x + s3.x);
        S.y = (s0.y + s1.y) + (s2.y + s3.y);
        S.z = (s0.z + s1.z) + (s2.z + s3.z);
        S.w = (s0.w + s1.w) + (s2.w + s3.w);
        M.x = fmaxf(fmaxf(m0.x, m1.x), fmaxf(m2.x, m3.x));
        M.y = fmaxf(fmaxf(m0.y, m1.y), fmaxf(m2.y, m3.y));
        M.z = fmaxf(fmaxf(m0.z, m1.z), fmaxf(m2.z, m3.z));
        M.w = fmaxf(fmaxf(m0.w, m1.w), fmaxf(m2.w, m3.w));

        const int w0 = 4 * tid;
        xcat2[128 + w0 + 0] = make_float2(S.x * (1.f / 128.f), M.x);
        xcat2[128 + w0 + 1] = make_float2(S.y * (1.f / 128.f), M.y);
        xcat2[128 + w0 + 2] = make_float2(S.z * (1.f / 128.f), M.z);
        xcat2[128 + w0 + 3] = make_float2(S.w * (1.f / 128.f), M.w);

        float gs = (S.x + S.y) + (S.z + S.w);
        float gm = fmaxf(fmaxf(M.x, M.y), fmaxf(M.z, M.w));
        #pragma unroll
        for (int m = 16; m >= 1; m >>= 1) {
            gs += __shfl_xor(gs, m);
            gm = fmaxf(gm, __shfl_xor(gm, m));
        }
        if (tid == 0) xcat2[256] = make_float2(gs * (1.f / 16384.f), gm);
    }
}

// y[n][s][t*2+k] = hswish(BN(einsum)) — grid N*9, 8-way c-split per s-chunk of 32
__global__ __launch_bounds__(256) void k2a_y(
    const float* __restrict__ xcat,
    const float* __restrict__ w1, const float* __restrict__ b1,
    const float* __restrict__ gam, const float* __restrict__ bet,
    const float* __restrict__ mu, const float* __restrict__ var,
    float* __restrict__ yg) {
    const int n = blockIdx.x / 9, sc = blockIdx.x % 9;
    const int tid = threadIdx.x;
    const int sl = tid & 31, cg = tid >> 5;

    __shared__ float w1s[TC_ * C_];           // 8 KB
    __shared__ float red[8][32 * 17];         // padded

    for (int i = tid; i < TC_ * C_; i += 256) w1s[i] = w1[i];
    __syncthreads();

    const int s = sc * 32 + sl;
    float acc[16];
    #pragma unroll
    for (int j = 0; j < 16; ++j) acc[j] = 0.f;

    if (s < S_) {
        const float2* xc = reinterpret_cast<const float2*>(xcat) + (size_t)n * C_ * S_;
        for (int ci = 0; ci < 32; ++ci) {
            const int c = cg * 32 + ci;
            const float2 v = xc[c * S_ + s];
            #pragma unroll
            for (int t = 0; t < TC_; ++t) {
                const float wv = w1s[t * C_ + c];
                acc[t * 2 + 0] += v.x * wv;
                acc[t * 2 + 1] += v.y * wv;
            }
        }
    }
    #pragma unroll
    for (int j = 0; j < 16; ++j) red[cg][sl * 17 + j] = acc[j];
    __syncthreads();

    // reduce 8 c-groups; thread (jj, sl2) handles j = 2*jj, 2*jj+1
    const int jj = tid >> 5, sl2 = tid & 31;
    const int s2 = sc * 32 + sl2;
    if (s2 < S_) {
        #pragma unroll
        for (int d = 0; d < 2; ++d) {
            const int j = jj * 2 + d;
            float v = 0.f;
            #pragma unroll
            for (int g = 0; g < 8; ++g) v += red[g][sl2 * 17 + j];
            const int t = j >> 1;
            const float inv = gam[t] * rsqrtf(var[t] + EPS_);
            float y = (v + b1[t] - mu[t]) * inv + bet[t];
            y = y * fminf(fmaxf(y + 3.f, 0.f), 6.f) * (1.f / 6.f);
            yg[((size_t)n * S_ + s2) * 16 + j] = y;
        }
    }
}

__global__ __launch_bounds__(256) void k2b_attn(
    const float* __restrict__ yg,
    const float* __restrict__ w2, const float* __restrict__ b2,
    const float* __restrict__ w3, const float* __restrict__ b3,
    const float* __restrict__ w4, const float* __restrict__ b4,
    float* __restrict__ a_h, float* __restrict__ a_w) {
    const int n = blockIdx.x;
    const int tid = threadIdx.x;

    __shared__ float w2s[C_ * 16];    // 16 KB
    __shared__ float w3s[C_ * 16];    // 16 KB
    __shared__ float ys[S_ * 17];     // padded, 17.5 KB
    __shared__ float acs[C_];

    for (int i = tid; i < C_ * 16; i += 256) { w2s[i] = w2[i]; w3s[i] = w3[i]; }
    for (int i = tid; i < S_ * 16; i += 256) {
        ys[(i >> 4) * 17 + (i & 15)] = yg[(size_t)n * S_ * 16 + i];
    }
    __syncthreads();

    // a_c per output channel o = tid
    {
        float z = b4[tid];
        const float4* w4v = reinterpret_cast<const float4*>(w4) + tid * 4;
        #pragma unroll
        for (int q = 0; q < 4; ++q) {
            const float4 ww = w4v[q];
            z += ys[256 * 17 + q * 4 + 0] * ww.x + ys[256 * 17 + q * 4 + 1] * ww.y +
                 ys[256 * 17 + q * 4 + 2] * ww.z + ys[256 * 17 + q * 4 + 3] * ww.w;
        }
        acs[tid] = 1.f / (1.f + expf(-z));
    }
    __syncthreads();

    const int hw = tid & 127, half = tid >> 7;
    float yh[16], yw[16];
    #pragma unroll
    for (int j = 0; j < 16; ++j) {
        yh[j] = ys[hw * 17 + j];
        yw[j] = ys[(128 + hw) * 17 + j];
    }
    for (int oo = 0; oo < 128; ++oo) {
        const int o = half * 128 + oo;
        float zh = b2[o], zw = b3[o];
        #pragma unroll
        for (int j = 0; j < 16; ++j) {
            zh += yh[j] * w2s[o * 16 + j];
            zw += yw[j] * w3s[o * 16 + j];
        }
        // fold a_c into a_h
        a_h[((size_t)n * C_ + o) * H_ + hw] = acs[o] / (1.f + expf(-zh));
        a_w[((size_t)n * C_ + o) * W_ + hw] = 1.f / (1.f + expf(-zw));
    }
}

__global__ __launch_bounds__(256) void k3_apply(
    const float* __restrict__ x, const float* __restrict__ a_h,
    const float* __restrict__ a_w, float* __restrict__ out) {
    // reverse block order: tail of x is hot in LLC after k1's forward stream.
    // nt stores keep `out` from allocating in the MALL and evicting x.
    const int bc = (N_ * C_ - 1) - blockIdx.x;
    const int tid = threadIdx.x;
    const f4n* x4 = reinterpret_cast<const f4n*>(x) + (size_t)bc * 4096;
    f4n* o4 = reinterpret_cast<f4n*>(out) + (size_t)bc * 4096;
    const float* ah = a_h + (size_t)bc * H_;   // includes a_c
    const float4* aw4 = reinterpret_cast<const float4*>(a_w) + (size_t)bc * 32;

    #pragma unroll
    for (int k = 0; k < 16; ++k) {
        const int i4 = k * 256 + tid;
        f4n v = x4[i4];                         // regular load: may hit LLC
        const float s = ah[i4 >> 5];
        const float4 a = aw4[i4 & 31];
        v.x *= s * a.x; v.y *= s * a.y; v.z *= s * a.z; v.w *= s * a.w;
        __builtin_nontemporal_store(v, &o4[i4]);
    }
}

extern "C" void kernel_launch(void* const* d_in, const int* in_sizes, int n_in,
                              void* d_out, int out_size, void* d_ws, size_t ws_size,
                              hipStream_t stream) {
    const float* x   = (const float*)d_in[0];
    const float* w1  = (const float*)d_in[1];
    const float* b1  = (const float*)d_in[2];
    const float* gam = (const float*)d_in[3];
    const float* bet = (const float*)d_in[4];
    const float* mu  = (const float*)d_in[5];
    const float* var = (const float*)d_in[6];
    const float* w2  = (const float*)d_in[7];
    const float* b2  = (const float*)d_in[8];
    const float* w3  = (const float*)d_in[9];
    const float* b3  = (const float*)d_in[10];
    const float* w4  = (const float*)d_in[11];
    const float* b4  = (const float*)d_in[12];

    float* ws   = (float*)d_ws;
    float* xcat = ws + XCAT_OFF;
    float* yg   = ws + Y_OFF;
    float* a_h  = ws + AH_OFF;
    float* a_w  = ws + AW_OFF;
    float* out  = (float*)d_out;

    k1_stats<<<N_ * C_, 256, 0, stream>>>(x, xcat);
    k2a_y<<<N_ * 9, 256, 0, stream>>>(xcat, w1, b1, gam, bet, mu, var, yg);
    k2b_attn<<<N_, 256, 0, stream>>>(yg, w2, b2, w3, b3, w4, b4, a_h, a_w);
    k3_apply<<<N_ * C_, 256, 0, stream>>>(x, a_h, a_w, out);
}